// Round 6
// baseline (484.052 us; speedup 1.0000x reference)
//
#include <hip/hip_runtime.h>

// NavierStokesLossMAC: B=8, H=W=1024
//   d_in[0] v_old (B,2,H,W) f32 | d_in[1] v_new (B,2,H,W) f32
//   d_in[2] p_new (B,1,H,W) f32 | d_in[3] mask  (B,1,H,W) i32
// out: (B,) f32
//
// R14: closed-loop latency model. R8-R13: time pinned 73-86us while bytes
// (196-344 MB), HBM (100-176 MB), VMEM instrs (343-780k), occupancy
// (24-37%) all varied -> no single rate binds; waves idle ~29k cycles in
// s_waitcnt because no structure had {optimal bytes, deep in-flight, no
// vmcnt-draining barrier} at once. R10 had bytes but __syncthreads drains
// vmcnt(0) every row (compiler-lowered); R11 had flight depth but 1.7x
// bytes. This kernel = R10's rolling window with the drain removed:
//  * per-row seam exchange via LDS + s_waitcnt lgkmcnt(0) + RAW s_barrier
//    (m201/T4 technique) -> global loads stay in flight across barriers.
//  * depth-3 named prefetch sets S0/S1/S2, 8-row body statically unrolled,
//    no set-to-set register copies -> ~18KB/wave always outstanding.
//  * bytes near-optimal: 10 v-rows + 9 p + 8 mask per 8-row chunk
//    = 234 MB requested (-32% vs R11).
//  * fused final reduce (atomic counter, self-resetting) -> 1 launch.
//  * XCD-bijective swizzle kept: 1024 blocks, each XCD owns one batch.

#define NS_H 1024
#define NS_W 1024
#define RY   8
#define NBY  128                      // row chunks per batch
#define NBLK (8 * NBY)                // 1024 blocks

__device__ __forceinline__ float4 ld4(const float* p) { return *(const float4*)p; }
__device__ __forceinline__ int4  ld4i(const int* p)   { return *(const int4*)p; }
__device__ __forceinline__ float4 avg4(float4 a, float4 b) {
    return make_float4(0.5f*(a.x+b.x), 0.5f*(a.y+b.y), 0.5f*(a.z+b.z), 0.5f*(a.w+b.w));
}
__device__ __forceinline__ float4 sub4(float4 a, float4 b) {
    return make_float4(a.x-b.x, a.y-b.y, a.z-b.z, a.w-b.w);
}

// raw barrier that does NOT drain vmcnt: only DS-visibility (lgkmcnt) is waited.
__device__ __forceinline__ void barrier_keep_loads_inflight() {
    __builtin_amdgcn_sched_barrier(0);
    asm volatile("s_waitcnt lgkmcnt(0)" ::: "memory");
    __builtin_amdgcn_s_barrier();
    __builtin_amdgcn_sched_barrier(0);
}

__global__ __launch_bounds__(256, 3) void ns_loss_fused(
    const float* __restrict__ v_old,
    const float* __restrict__ v_new,
    const float* __restrict__ p,
    const int*   __restrict__ mask,
    float* __restrict__ ws,
    unsigned*   __restrict__ cnt,
    float* __restrict__ out)
{
    // XCD-bijective swizzle over 1024 blocks: XCD k owns batch k
    const int blkp = blockIdx.x;
    const int lg   = (blkp & 7) * NBY + (blkp >> 3);
    const int b    = lg / NBY;
    const int cy   = lg % NBY;
    const int y0   = 1 + cy * RY;      // rows y0..y0+7 (tail rows masked)

    const size_t hw = (size_t)NS_H * NS_W;
    const float* uo = v_old + (size_t)b * 2 * hw;
    const float* wo = uo + hw;
    const float* un = v_new + (size_t)b * 2 * hw;
    const float* wn = un + hw;
    const float* pb = p    + (size_t)b * hw;
    const int*   mb = mask + (size_t)b * hw;

    const int tid  = (int)threadIdx.x;
    const int lane = tid & 63;
    const int wid  = tid >> 6;
    const int x0   = tid * 4;
    const bool has_r = (tid != 255);   // false only for x0==1020 (feeds masked x=1023)

    // seam exchange buffers, double-buffered by row parity
    __shared__ float edge[2][4][5];

    // ---- prologue: window rows y0-1, y0, y0+1 (no clamp needed) ----
    const int off_m = (y0 - 1) * NS_W + x0;
    const int off_c = off_m + NS_W;
    const int off_p = off_c + NS_W;

    float4 t0 = ld4(un + off_m), t1 = ld4(uo + off_m);
    float4 t2 = ld4(wn + off_m), t3 = ld4(wo + off_m);
    float4 t4 = ld4(un + off_c), t5 = ld4(uo + off_c);
    float4 t6 = ld4(wn + off_c), t7 = ld4(wo + off_c);
    float4 t8 = ld4(un + off_p), t9 = ld4(uo + off_p);
    float4 ta = ld4(wn + off_p), tb = ld4(wo + off_p);
    float4 p_m4 = ld4(pb + off_m);
    float4 p_c4 = ld4(pb + off_c);
    int4   m_c4 = ld4i(mb + off_c);

    // ---- depth-3 in-flight sets (set consumed at end of row r holds
    //      v row y0+r+2, p/mask row y0+r+1); prologue issues r=0,1,2 ----
    const int ov0 = (y0 + 2) * NS_W + x0, on0 = (y0 + 1) * NS_W + x0;
    const int ov1 = (y0 + 3) * NS_W + x0, on1 = (y0 + 2) * NS_W + x0;
    const int ov2 = (y0 + 4) * NS_W + x0, on2 = (y0 + 3) * NS_W + x0;
    float4 a_un = ld4(un + ov0), a_uo = ld4(uo + ov0);
    float4 a_wn = ld4(wn + ov0), a_wo = ld4(wo + ov0);
    float4 a_p  = ld4(pb + on0); int4 a_m = ld4i(mb + on0);
    float4 b_un = ld4(un + ov1), b_uo = ld4(uo + ov1);
    float4 b_wn = ld4(wn + ov1), b_wo = ld4(wo + ov1);
    float4 b_p  = ld4(pb + on1); int4 b_m = ld4i(mb + on1);
    float4 c_un = ld4(un + ov2), c_uo = ld4(uo + ov2);
    float4 c_wn = ld4(wn + ov2), c_wo = ld4(wo + ov2);
    float4 c_p  = ld4(pb + on2); int4 c_m = ld4i(mb + on2);
    __builtin_amdgcn_sched_barrier(0);    // all 31 loads issued before compute

    float4 u_m = avg4(t0, t1), w_m = avg4(t2, t3);
    float4 u_c = avg4(t4, t5), du_c = sub4(t4, t5);
    float4 w_c = avg4(t6, t7), dw_c = sub4(t6, t7);
    float4 u_p = avg4(t8, t9), du_p = sub4(t8, t9);
    float4 w_p = avg4(ta, tb), dw_p = sub4(ta, tb);

    float acc = 0.f;

    auto iter = [&](int r, bool consume, bool reissue,
                    float4& g_un, float4& g_uo, float4& g_wn, float4& g_wo,
                    float4& g_p, int4& g_m) {
        const int y   = y0 + r;
        const int par = r & 1;

        // publish this row's block-internal seam values (register-sourced)
        if (lane == 63) {
            edge[par][wid][0] = u_c.w; edge[par][wid][1] = w_c.w; edge[par][wid][2] = p_c4.w;
        }
        if (lane == 0) {
            edge[par][wid][3] = u_c.x; edge[par][wid][4] = w_c.x;
        }
        barrier_keep_loads_inflight();

        float ul = __shfl_up(u_c.w, 1), wl = __shfl_up(w_c.w, 1), pl = __shfl_up(p_c4.w, 1);
        if (lane == 0 && wid > 0) {
            ul = edge[par][wid-1][0]; wl = edge[par][wid-1][1]; pl = edge[par][wid-1][2];
        }
        float ur = __shfl_down(u_c.x, 1), wr = __shfl_down(w_c.x, 1);
        if (lane == 63 && wid < 3) {
            ur = edge[par][wid+1][3]; wr = edge[par][wid+1][4];
        }
        if (!has_r) { ur = 0.f; wr = 0.f; }   // feeds masked x=1023 only

        const float rowvalid = (y <= NS_H - 2) ? 1.f : 0.f;
        {
            const float uc[6]  = {ul, u_c.x, u_c.y, u_c.z, u_c.w, ur};
            const float wcv[6] = {wl, w_c.x, w_c.y, w_c.z, w_c.w, wr};
            const float uym[4] = {u_m.x, u_m.y, u_m.z, u_m.w};
            const float uyp[4] = {u_p.x, u_p.y, u_p.z, u_p.w};
            const float wym[4] = {w_m.x, w_m.y, w_m.z, w_m.w};
            const float wyp[4] = {w_p.x, w_p.y, w_p.z, w_p.w};
            const float du[4]  = {du_c.x, du_c.y, du_c.z, du_c.w};
            const float dw[4]  = {dw_c.x, dw_c.y, dw_c.z, dw_c.w};
            const float pcv[5] = {pl, p_c4.x, p_c4.y, p_c4.z, p_c4.w};
            const float pym[4] = {p_m4.x, p_m4.y, p_m4.z, p_m4.w};
            const int   mm[4]  = {m_c4.x, m_c4.y, m_c4.z, m_c4.w};

            #pragma unroll
            for (int j = 0; j < 4; ++j) {
                const int x = x0 + j;
                const float m = ((x >= 1 && x <= NS_W - 2) ? (float)mm[j] : 0.f) * rowvalid;
                const float u_cc = uc[j+1],  u_xm = uc[j],  u_xp = uc[j+2];
                const float w_cc = wcv[j+1], w_xm = wcv[j], w_xp = wcv[j+2];

                float res_x =
                    dw[j] * 0.25f
                  + w_cc * 0.5f * (w_xp - w_xm)
                  + 0.5f * ( 0.5f * (u_cc + u_xm) * (w_cc   - wym[j])
                           + 0.5f * (u_cc + u_xp) * (wyp[j] - w_cc  ) )
                  + (pcv[j+1] - pcv[j])
                  - 0.1f * (w_xm + w_xp + wym[j] + wyp[j] - 4.f * w_cc);

                float res_y =
                    du[j] * 0.25f
                  + u_cc * 0.5f * (uyp[j] - uym[j])
                  + 0.5f * ( 0.5f * (w_cc + wym[j]) * (u_cc - u_xm)
                           + 0.5f * (w_cc + wyp[j]) * (u_xp - u_cc) )
                  + (pcv[j+1] - pym[j])
                  - 0.1f * (u_xm + u_xp + uym[j] + uyp[j] - 4.f * u_cc);

                acc += m * (res_x * res_x + res_y * res_y);
            }
        }

        if (consume) {
            // rotate window, consuming this row's in-flight set
            u_m = u_c;  w_m = w_c;
            u_c = u_p;  w_c = w_p;  du_c = du_p;  dw_c = dw_p;
            u_p = avg4(g_un, g_uo); du_p = sub4(g_un, g_uo);
            w_p = avg4(g_wn, g_wo); dw_p = sub4(g_wn, g_wo);
            p_m4 = p_c4; p_c4 = g_p; m_c4 = g_m;
        }
        if (reissue) {
            // reissue same set for consumption at row r+3:
            // v row y+5, p/mask row y+4 (clamped; tail rows masked anyway)
            int rv = y + 5; if (rv > NS_H - 1) rv = NS_H - 1;
            int rn = y + 4; if (rn > NS_H - 1) rn = NS_H - 1;
            const int ov = rv * NS_W + x0;
            const int on = rn * NS_W + x0;
            g_un = ld4(un + ov); g_uo = ld4(uo + ov);
            g_wn = ld4(wn + ov); g_wo = ld4(wo + ov);
            g_p  = ld4(pb + on); g_m  = ld4i(mb + on);
        }
    };

    // 8 rows, statically unrolled; sets cycle S0,S1,S2
    iter(0, true,  true,  a_un, a_uo, a_wn, a_wo, a_p, a_m);
    iter(1, true,  true,  b_un, b_uo, b_wn, b_wo, b_p, b_m);
    iter(2, true,  true,  c_un, c_uo, c_wn, c_wo, c_p, c_m);
    iter(3, true,  true,  a_un, a_uo, a_wn, a_wo, a_p, a_m);
    iter(4, true,  false, b_un, b_uo, b_wn, b_wo, b_p, b_m);
    iter(5, true,  false, c_un, c_uo, c_wn, c_wo, c_p, c_m);
    iter(6, true,  false, a_un, a_uo, a_wn, a_wo, a_p, a_m);
    iter(7, false, false, a_un, a_uo, a_wn, a_wo, a_p, a_m);

    // ---- block reduction ----
    #pragma unroll
    for (int off = 32; off > 0; off >>= 1)
        acc += __shfl_down(acc, off);

    __shared__ float smem[4];
    if (lane == 0) smem[wid] = acc;
    __syncthreads();

    if (tid == 0)
        ws[lg] = smem[0] + smem[1] + smem[2] + smem[3];

    // ---- fused final reduce: last block sums all partials ----
    __threadfence();                       // release partial store
    __shared__ unsigned s_done;
    if (tid == 0) {
        unsigned old = atomicAdd(cnt, 1u);
        s_done = (old == (unsigned)(NBLK - 1)) ? 1u : 0u;
    }
    __syncthreads();

    if (s_done) {
        __threadfence();                   // acquire others' partial stores
        const float inv = 1.0f / ((float)(NS_H - 2) * (float)(NS_W - 2));
        #pragma unroll
        for (int bb = wid; bb < 8; bb += 4) {
            float a = ws[bb * NBY + lane] + ws[bb * NBY + 64 + lane];
            #pragma unroll
            for (int off = 32; off > 0; off >>= 1)
                a += __shfl_down(a, off);
            if (lane == 0) out[bb] = a * inv;
        }
        if (tid == 0) *cnt = 0;            // self-reset for next graph replay
    }
}

extern "C" void kernel_launch(void* const* d_in, const int* in_sizes, int n_in,
                              void* d_out, int out_size, void* d_ws, size_t ws_size,
                              hipStream_t stream) {
    const float* v_old = (const float*)d_in[0];
    const float* v_new = (const float*)d_in[1];
    const float* p_new = (const float*)d_in[2];
    const int*   msk   = (const int*)d_in[3];
    float* out = (float*)d_out;
    float* ws  = (float*)d_ws;
    unsigned* cnt = (unsigned*)(ws + NBLK);   // 4 bytes after the partials

    hipMemsetAsync(cnt, 0, sizeof(unsigned), stream);   // belt & braces; capturable
    ns_loss_fused<<<dim3(NBLK), dim3(256), 0, stream>>>(v_old, v_new, p_new, msk,
                                                        ws, cnt, out);
}

// Round 8
// 209.537 us; speedup vs baseline: 2.3101x; 2.3101x over previous
//
#include <hip/hip_runtime.h>

// NavierStokesLossMAC: B=8, H=W=1024
//   d_in[0] v_old (B,2,H,W) f32 | d_in[1] v_new (B,2,H,W) f32
//   d_in[2] p_new (B,1,H,W) f32 | d_in[3] mask  (B,1,H,W) i32
// out: (B,) f32
//
// R16 == R15 resubmitted (round 7 bench died in infra, kernel never ran).
// Two-phase one-shot, RY=4. Clean one-shot kernels (R8/R11/R13) all
// run 4.6-4.8 TB/s L2->L1 fill on ~350 MB requested -> 73-75us. Every
// lower-byte attempt died of a confound: R10 per-row vmcnt drain, R12/R14
// register spill (WRITE_SIZE canary 16/167 MB). This kernel removes bytes
// with neither confound:
//  * Phase A == R11 verbatim: 21-load burst (rows y-1..y+2), computes
//    rows y,y+1. Phase B: only NEW data (12 loads: v y+3,y+4; p,m y+2,y+3),
//    computes rows y+2,y+3 reusing A's derived registers.
//  * 33 loads / 4 rows = 276 MB requested (-22% vs R11).
//  * B loads issue after A's seam-sync (vmcnt naturally 0 there -> barrier
//    drain free) and before A's stencil, pinned by sched_barrier(0):
//    B latency hides under A arithmetic. Both syncthreads sit at
//    in-flight==0 points.
//  * Peak live ~ A-derived(19 f4) + B-raw(12 f4) ~ 150 VGPR < 170 cap ->
//    no spill (canary: WRITE_SIZE must stay KB-scale).
//  * XCD-bijective swizzle kept (2048 blocks, %8==0).

#define NS_H 1024
#define NS_W 1024
#define RPB 4
#define NBY 256                       // chunks per batch; tail chunk: 2 valid rows
#define PARTS_PER_B NBY

__device__ __forceinline__ float4 ld4(const float* p) { return *(const float4*)p; }
__device__ __forceinline__ int4  ld4i(const int* p)   { return *(const int4*)p; }
__device__ __forceinline__ float4 avg4(float4 a, float4 b) {
    return make_float4(0.5f*(a.x+b.x), 0.5f*(a.y+b.y), 0.5f*(a.z+b.z), 0.5f*(a.w+b.w));
}
__device__ __forceinline__ float4 sub4(float4 a, float4 b) {
    return make_float4(a.x-b.x, a.y-b.y, a.z-b.z, a.w-b.w);
}

__global__ __launch_bounds__(256, 3) void ns_loss_partial(
    const float* __restrict__ v_old,
    const float* __restrict__ v_new,
    const float* __restrict__ p,
    const int*   __restrict__ mask,
    float* __restrict__ ws)
{
    // XCD-bijective swizzle over 2048 blocks (2048 % 8 == 0)
    const int blkp = blockIdx.x;
    const int lg   = (blkp & 7) * NBY + (blkp >> 3);
    const int b    = lg / NBY;
    const int cy   = lg % NBY;
    const int y0   = 1 + cy * RPB;    // output rows y0..y0+3 (last two validity-masked)

    const size_t hw = (size_t)NS_H * NS_W;
    const float* uo = v_old + (size_t)b * 2 * hw;
    const float* wo = uo + hw;
    const float* un = v_new + (size_t)b * 2 * hw;
    const float* wn = un + hw;
    const float* pb = p    + (size_t)b * hw;
    const int*   mb = mask + (size_t)b * hw;

    const int tid  = (int)threadIdx.x;
    const int lane = tid & 63;
    const int wid  = tid >> 6;
    const int x0   = tid * 4;
    const bool has_r = (tid != 255);  // false only for x0==1020 (feeds masked x=1023)

    // rows: Rm=y0-1, Rc=y0, Rp=y0+1, Rq=y0+2 (all <=1023); Rr,Rs clamp on tail
    const int rm  = (y0 - 1) * NS_W;
    const int rc  = rm + NS_W;
    const int rp  = rc + NS_W;
    const int rq  = rp + NS_W;
    int Rr = y0 + 3; if (Rr > 1023) Rr = 1023;
    int Rs = y0 + 4; if (Rs > 1023) Rs = 1023;
    const int rr = Rr * NS_W;
    const int rs = Rs * NS_W;
    const float rv_q = (y0 + 2 <= NS_H - 2) ? 1.f : 0.f;
    const float rv_r = (y0 + 3 <= NS_H - 2) ? 1.f : 0.f;

    __shared__ float edge[2][4][10];

    // ================= PHASE A: 21-load burst (== R11) =================
    float4 un_m = ld4(un + rm + x0), uo_m = ld4(uo + rm + x0);
    float4 un_c = ld4(un + rc + x0), uo_c = ld4(uo + rc + x0);
    float4 un_p = ld4(un + rp + x0), uo_p = ld4(uo + rp + x0);
    float4 un_q = ld4(un + rq + x0), uo_q = ld4(uo + rq + x0);
    float4 wn_m = ld4(wn + rm + x0), wo_m = ld4(wo + rm + x0);
    float4 wn_c = ld4(wn + rc + x0), wo_c = ld4(wo + rc + x0);
    float4 wn_p = ld4(wn + rp + x0), wo_p = ld4(wo + rp + x0);
    float4 wn_q = ld4(wn + rq + x0), wo_q = ld4(wo + rq + x0);
    float4 p_m4 = ld4(pb + rm + x0);
    float4 p_c4 = ld4(pb + rc + x0);
    float4 p_p4 = ld4(pb + rp + x0);
    int4   m_c4 = ld4i(mb + rc + x0);
    int4   m_p4 = ld4i(mb + rp + x0);
    __builtin_amdgcn_sched_barrier(0);   // all 21 A-loads issued before any compute

    float4 u_m = avg4(un_m, uo_m), u_c = avg4(un_c, uo_c);
    float4 u_p = avg4(un_p, uo_p), u_q = avg4(un_q, uo_q);
    float4 w_m = avg4(wn_m, wo_m), w_c = avg4(wn_c, wo_c);
    float4 w_p = avg4(wn_p, wo_p), w_q = avg4(wn_q, wo_q);
    float4 du_c = sub4(un_c, uo_c), du_p = sub4(un_p, uo_p);
    float4 dw_c = sub4(wn_c, wo_c), dw_p = sub4(wn_p, wo_p);
    float4 du_q = sub4(un_q, uo_q), dw_q = sub4(wn_q, wo_q);   // carried to phase B

    // ---- A seam exchange (rows Rc,Rp); in-flight == 0 here -> drain free ----
    if (lane == 63) {
        edge[0][wid][0] = u_c.w;  edge[0][wid][1] = w_c.w;  edge[0][wid][2] = p_c4.w;
        edge[0][wid][3] = u_p.w;  edge[0][wid][4] = w_p.w;  edge[0][wid][5] = p_p4.w;
    }
    if (lane == 0) {
        edge[0][wid][6] = u_c.x;  edge[0][wid][7] = w_c.x;
        edge[0][wid][8] = u_p.x;  edge[0][wid][9] = w_p.x;
    }
    __syncthreads();

    float ul_c = __shfl_up(u_c.w, 1),  wl_c = __shfl_up(w_c.w, 1);
    float ul_p = __shfl_up(u_p.w, 1),  wl_p = __shfl_up(w_p.w, 1);
    float pl_c = __shfl_up(p_c4.w, 1), pl_p = __shfl_up(p_p4.w, 1);
    if (lane == 0 && wid > 0) {
        ul_c = edge[0][wid-1][0]; wl_c = edge[0][wid-1][1]; pl_c = edge[0][wid-1][2];
        ul_p = edge[0][wid-1][3]; wl_p = edge[0][wid-1][4]; pl_p = edge[0][wid-1][5];
    }
    float ur_c = __shfl_down(u_c.x, 1), wr_c = __shfl_down(w_c.x, 1);
    float ur_p = __shfl_down(u_p.x, 1), wr_p = __shfl_down(w_p.x, 1);
    if (lane == 63 && wid < 3) {
        ur_c = edge[0][wid+1][6]; wr_c = edge[0][wid+1][7];
        ur_p = edge[0][wid+1][8]; wr_p = edge[0][wid+1][9];
    }
    if (!has_r) { ur_c = 0.f; wr_c = 0.f; ur_p = 0.f; wr_p = 0.f; }

    // ================= PHASE B loads: 12, in flight under A stencil =========
    float4 un_r = ld4(un + rr + x0), uo_r = ld4(uo + rr + x0);
    float4 wn_r = ld4(wn + rr + x0), wo_r = ld4(wo + rr + x0);
    float4 un_s = ld4(un + rs + x0), uo_s = ld4(uo + rs + x0);
    float4 wn_s = ld4(wn + rs + x0), wo_s = ld4(wo + rs + x0);
    float4 p_q4 = ld4(pb + rq + x0);
    float4 p_r4 = ld4(pb + rr + x0);
    int4   m_q4 = ld4i(mb + rq + x0);
    int4   m_r4 = ld4i(mb + rr + x0);
    __builtin_amdgcn_sched_barrier(0);   // pin B-loads above A stencil

    float acc = 0.f;

    // ---- A stencil row Rc: y- = Rm, y+ = Rp ----
    {
        const float uc[6]  = {ul_c, u_c.x, u_c.y, u_c.z, u_c.w, ur_c};
        const float wcv[6] = {wl_c, w_c.x, w_c.y, w_c.z, w_c.w, wr_c};
        const float uym[4] = {u_m.x, u_m.y, u_m.z, u_m.w};
        const float uyp[4] = {u_p.x, u_p.y, u_p.z, u_p.w};
        const float wym[4] = {w_m.x, w_m.y, w_m.z, w_m.w};
        const float wyp[4] = {w_p.x, w_p.y, w_p.z, w_p.w};
        const float du[4]  = {du_c.x, du_c.y, du_c.z, du_c.w};
        const float dw[4]  = {dw_c.x, dw_c.y, dw_c.z, dw_c.w};
        const float pcv[5] = {pl_c, p_c4.x, p_c4.y, p_c4.z, p_c4.w};
        const float pym[4] = {p_m4.x, p_m4.y, p_m4.z, p_m4.w};
        const int   mm[4]  = {m_c4.x, m_c4.y, m_c4.z, m_c4.w};

        #pragma unroll
        for (int j = 0; j < 4; ++j) {
            const int x = x0 + j;
            const float m = (x >= 1 && x <= NS_W - 2) ? (float)mm[j] : 0.f;
            const float u_cc = uc[j+1],  u_xm = uc[j],  u_xp = uc[j+2];
            const float w_cc = wcv[j+1], w_xm = wcv[j], w_xp = wcv[j+2];

            float res_x =
                dw[j] * 0.25f
              + w_cc * 0.5f * (w_xp - w_xm)
              + 0.5f * ( 0.5f * (u_cc + u_xm) * (w_cc   - wym[j])
                       + 0.5f * (u_cc + u_xp) * (wyp[j] - w_cc  ) )
              + (pcv[j+1] - pcv[j])
              - 0.1f * (w_xm + w_xp + wym[j] + wyp[j] - 4.f * w_cc);

            float res_y =
                du[j] * 0.25f
              + u_cc * 0.5f * (uyp[j] - uym[j])
              + 0.5f * ( 0.5f * (w_cc + wym[j]) * (u_cc - u_xm)
                       + 0.5f * (w_cc + wyp[j]) * (u_xp - u_cc) )
              + (pcv[j+1] - pym[j])
              - 0.1f * (u_xm + u_xp + uym[j] + uyp[j] - 4.f * u_cc);

            acc += m * (res_x * res_x + res_y * res_y);
        }
    }

    // ---- A stencil row Rp: y- = Rc, y+ = Rq ----
    {
        const float uc[6]  = {ul_p, u_p.x, u_p.y, u_p.z, u_p.w, ur_p};
        const float wcv[6] = {wl_p, w_p.x, w_p.y, w_p.z, w_p.w, wr_p};
        const float uym[4] = {u_c.x, u_c.y, u_c.z, u_c.w};
        const float uyp[4] = {u_q.x, u_q.y, u_q.z, u_q.w};
        const float wym[4] = {w_c.x, w_c.y, w_c.z, w_c.w};
        const float wyp[4] = {w_q.x, w_q.y, w_q.z, w_q.w};
        const float du[4]  = {du_p.x, du_p.y, du_p.z, du_p.w};
        const float dw[4]  = {dw_p.x, dw_p.y, dw_p.z, dw_p.w};
        const float pcv[5] = {pl_p, p_p4.x, p_p4.y, p_p4.z, p_p4.w};
        const float pym[4] = {p_c4.x, p_c4.y, p_c4.z, p_c4.w};
        const int   mm[4]  = {m_p4.x, m_p4.y, m_p4.z, m_p4.w};

        #pragma unroll
        for (int j = 0; j < 4; ++j) {
            const int x = x0 + j;
            const float m = (x >= 1 && x <= NS_W - 2) ? (float)mm[j] : 0.f;
            const float u_cc = uc[j+1],  u_xm = uc[j],  u_xp = uc[j+2];
            const float w_cc = wcv[j+1], w_xm = wcv[j], w_xp = wcv[j+2];

            float res_x =
                dw[j] * 0.25f
              + w_cc * 0.5f * (w_xp - w_xm)
              + 0.5f * ( 0.5f * (u_cc + u_xm) * (w_cc   - wym[j])
                       + 0.5f * (u_cc + u_xp) * (wyp[j] - w_cc  ) )
              + (pcv[j+1] - pcv[j])
              - 0.1f * (w_xm + w_xp + wym[j] + wyp[j] - 4.f * w_cc);

            float res_y =
                du[j] * 0.25f
              + u_cc * 0.5f * (uyp[j] - uym[j])
              + 0.5f * ( 0.5f * (w_cc + wym[j]) * (u_cc - u_xm)
                       + 0.5f * (w_cc + wyp[j]) * (u_xp - u_cc) )
              + (pcv[j+1] - pym[j])
              - 0.1f * (u_xm + u_xp + uym[j] + uyp[j] - 4.f * u_cc);

            acc += m * (res_x * res_x + res_y * res_y);
        }
    }

    // ================= PHASE B derived + seams + stencil =================
    float4 u_r = avg4(un_r, uo_r), w_r = avg4(wn_r, wo_r);
    float4 du_r = sub4(un_r, uo_r), dw_r = sub4(wn_r, wo_r);
    float4 u_s = avg4(un_s, uo_s), w_s = avg4(wn_s, wo_s);

    // B seam exchange (rows Rq,Rr); B loads consumed -> in-flight == 0 -> free
    if (lane == 63) {
        edge[1][wid][0] = u_q.w;  edge[1][wid][1] = w_q.w;  edge[1][wid][2] = p_q4.w;
        edge[1][wid][3] = u_r.w;  edge[1][wid][4] = w_r.w;  edge[1][wid][5] = p_r4.w;
    }
    if (lane == 0) {
        edge[1][wid][6] = u_q.x;  edge[1][wid][7] = w_q.x;
        edge[1][wid][8] = u_r.x;  edge[1][wid][9] = w_r.x;
    }
    __syncthreads();

    float ul_q = __shfl_up(u_q.w, 1),  wl_q = __shfl_up(w_q.w, 1);
    float ul_r = __shfl_up(u_r.w, 1),  wl_r = __shfl_up(w_r.w, 1);
    float pl_q = __shfl_up(p_q4.w, 1), pl_r = __shfl_up(p_r4.w, 1);
    if (lane == 0 && wid > 0) {
        ul_q = edge[1][wid-1][0]; wl_q = edge[1][wid-1][1]; pl_q = edge[1][wid-1][2];
        ul_r = edge[1][wid-1][3]; wl_r = edge[1][wid-1][4]; pl_r = edge[1][wid-1][5];
    }
    float ur_q = __shfl_down(u_q.x, 1), wr_q = __shfl_down(w_q.x, 1);
    float ur_r = __shfl_down(u_r.x, 1), wr_r = __shfl_down(w_r.x, 1);
    if (lane == 63 && wid < 3) {
        ur_q = edge[1][wid+1][6]; wr_q = edge[1][wid+1][7];
        ur_r = edge[1][wid+1][8]; wr_r = edge[1][wid+1][9];
    }
    if (!has_r) { ur_q = 0.f; wr_q = 0.f; ur_r = 0.f; wr_r = 0.f; }

    // ---- B stencil row Rq: y- = Rp, y+ = Rr ----
    {
        const float uc[6]  = {ul_q, u_q.x, u_q.y, u_q.z, u_q.w, ur_q};
        const float wcv[6] = {wl_q, w_q.x, w_q.y, w_q.z, w_q.w, wr_q};
        const float uym[4] = {u_p.x, u_p.y, u_p.z, u_p.w};
        const float uyp[4] = {u_r.x, u_r.y, u_r.z, u_r.w};
        const float wym[4] = {w_p.x, w_p.y, w_p.z, w_p.w};
        const float wyp[4] = {w_r.x, w_r.y, w_r.z, w_r.w};
        const float du[4]  = {du_q.x, du_q.y, du_q.z, du_q.w};
        const float dw[4]  = {dw_q.x, dw_q.y, dw_q.z, dw_q.w};
        const float pcv[5] = {pl_q, p_q4.x, p_q4.y, p_q4.z, p_q4.w};
        const float pym[4] = {p_p4.x, p_p4.y, p_p4.z, p_p4.w};
        const int   mm[4]  = {m_q4.x, m_q4.y, m_q4.z, m_q4.w};

        #pragma unroll
        for (int j = 0; j < 4; ++j) {
            const int x = x0 + j;
            const float m = ((x >= 1 && x <= NS_W - 2) ? (float)mm[j] : 0.f) * rv_q;
            const float u_cc = uc[j+1],  u_xm = uc[j],  u_xp = uc[j+2];
            const float w_cc = wcv[j+1], w_xm = wcv[j], w_xp = wcv[j+2];

            float res_x =
                dw[j] * 0.25f
              + w_cc * 0.5f * (w_xp - w_xm)
              + 0.5f * ( 0.5f * (u_cc + u_xm) * (w_cc   - wym[j])
                       + 0.5f * (u_cc + u_xp) * (wyp[j] - w_cc  ) )
              + (pcv[j+1] - pcv[j])
              - 0.1f * (w_xm + w_xp + wym[j] + wyp[j] - 4.f * w_cc);

            float res_y =
                du[j] * 0.25f
              + u_cc * 0.5f * (uyp[j] - uym[j])
              + 0.5f * ( 0.5f * (w_cc + wym[j]) * (u_cc - u_xm)
                       + 0.5f * (w_cc + wyp[j]) * (u_xp - u_cc) )
              + (pcv[j+1] - pym[j])
              - 0.1f * (u_xm + u_xp + uym[j] + uyp[j] - 4.f * u_cc);

            acc += m * (res_x * res_x + res_y * res_y);
        }
    }

    // ---- B stencil row Rr: y- = Rq, y+ = Rs ----
    {
        const float uc[6]  = {ul_r, u_r.x, u_r.y, u_r.z, u_r.w, ur_r};
        const float wcv[6] = {wl_r, w_r.x, w_r.y, w_r.z, w_r.w, wr_r};
        const float uym[4] = {u_q.x, u_q.y, u_q.z, u_q.w};
        const float uyp[4] = {u_s.x, u_s.y, u_s.z, u_s.w};
        const float wym[4] = {w_q.x, w_q.y, w_q.z, w_q.w};
        const float wyp[4] = {w_s.x, w_s.y, w_s.z, w_s.w};
        const float du[4]  = {du_r.x, du_r.y, du_r.z, du_r.w};
        const float dw[4]  = {dw_r.x, dw_r.y, dw_r.z, dw_r.w};
        const float pcv[5] = {pl_r, p_r4.x, p_r4.y, p_r4.z, p_r4.w};
        const float pym[4] = {p_q4.x, p_q4.y, p_q4.z, p_q4.w};
        const int   mm[4]  = {m_r4.x, m_r4.y, m_r4.z, m_r4.w};

        #pragma unroll
        for (int j = 0; j < 4; ++j) {
            const int x = x0 + j;
            const float m = ((x >= 1 && x <= NS_W - 2) ? (float)mm[j] : 0.f) * rv_r;
            const float u_cc = uc[j+1],  u_xm = uc[j],  u_xp = uc[j+2];
            const float w_cc = wcv[j+1], w_xm = wcv[j], w_xp = wcv[j+2];

            float res_x =
                dw[j] * 0.25f
              + w_cc * 0.5f * (w_xp - w_xm)
              + 0.5f * ( 0.5f * (u_cc + u_xm) * (w_cc   - wym[j])
                       + 0.5f * (u_cc + u_xp) * (wyp[j] - w_cc  ) )
              + (pcv[j+1] - pcv[j])
              - 0.1f * (w_xm + w_xp + wym[j] + wyp[j] - 4.f * w_cc);

            float res_y =
                du[j] * 0.25f
              + u_cc * 0.5f * (uyp[j] - uym[j])
              + 0.5f * ( 0.5f * (w_cc + wym[j]) * (u_cc - u_xm)
                       + 0.5f * (w_cc + wyp[j]) * (u_xp - u_cc) )
              + (pcv[j+1] - pym[j])
              - 0.1f * (u_xm + u_xp + uym[j] + uyp[j] - 4.f * u_cc);

            acc += m * (res_x * res_x + res_y * res_y);
        }
    }

    // ---- block reduction: wave shuffle -> 16B LDS -> one plain store ----
    #pragma unroll
    for (int off = 32; off > 0; off >>= 1)
        acc += __shfl_down(acc, off);

    __shared__ float smem[4];
    if (lane == 0) smem[wid] = acc;
    __syncthreads();

    if (tid == 0)
        ws[lg] = smem[0] + smem[1] + smem[2] + smem[3];
}

__global__ __launch_bounds__(256) void ns_loss_reduce(
    const float* __restrict__ ws, float* __restrict__ out)
{
    const int b = blockIdx.x;
    float acc = 0.f;
    for (int i = threadIdx.x; i < PARTS_PER_B; i += 256)
        acc += ws[b * PARTS_PER_B + i];

    #pragma unroll
    for (int off = 32; off > 0; off >>= 1)
        acc += __shfl_down(acc, off);

    __shared__ float smem[4];
    const int lane = threadIdx.x & 63;
    const int wid  = threadIdx.x >> 6;
    if (lane == 0) smem[wid] = acc;
    __syncthreads();

    if (threadIdx.x == 0) {
        const float inv = 1.0f / ((float)(NS_H - 2) * (float)(NS_W - 2));
        out[b] = (smem[0] + smem[1] + smem[2] + smem[3]) * inv;
    }
}

extern "C" void kernel_launch(void* const* d_in, const int* in_sizes, int n_in,
                              void* d_out, int out_size, void* d_ws, size_t ws_size,
                              hipStream_t stream) {
    const float* v_old = (const float*)d_in[0];
    const float* v_new = (const float*)d_in[1];
    const float* p_new = (const float*)d_in[2];
    const int*   msk   = (const int*)d_in[3];
    float* out = (float*)d_out;
    float* ws  = (float*)d_ws;

    const int B = out_size;   // 8

    ns_loss_partial<<<dim3(B * NBY), dim3(256), 0, stream>>>(v_old, v_new, p_new, msk, ws);
    ns_loss_reduce<<<dim3(B), dim3(256), 0, stream>>>(ws, out);
}

// Round 9
// 204.182 us; speedup vs baseline: 2.3707x; 1.0262x over previous
//
#include <hip/hip_runtime.h>

// NavierStokesLossMAC: B=8, H=W=1024
//   d_in[0] v_old (B,2,H,W) f32 | d_in[1] v_new (B,2,H,W) f32
//   d_in[2] p_new (B,1,H,W) f32 | d_in[3] mask  (B,1,H,W) i32
// out: (B,) f32
//
// R17: global_load_lds pipeline. Three rounds (R12/R14/R16) proved the
// allocator spills past ~21 live float4 loads (VGPR pinned 84, WRITE_SIZE
// 16/167/29 MB canary) -> byte reduction is impossible through the register
// file. R10 proved __syncthreads drains vmcnt(0) every row. This kernel
// breaks the {bytes, depth, no-drain} trilemma with direct-to-LDS staging:
//  * 128-thr block = 512-col x 32-row tile; 4-deep LDS ring of
//    {un,uo,wn,wo,p,mask} 512-float rows (48KB) + 1KB x-halo scratch.
//  * per iter: raw s_barrier (WAR guard) -> stage row-set r+3 via 6/7
//    global_load_lds per wave (zero VGPR cost) -> counted s_waitcnt
//    vmcnt(6/7) (never 0 mid-loop; T3/T4) -> raw s_barrier -> stencil
//    reads from LDS. Loads stay in flight across barriers.
//  * x-halo: one 4B-per-lane gather instr per row-set (9 lanes fetch the
//    edge scalars of all arrays) into es[slot][..].
//  * bytes: v 34/32 rows + p + mask = 204 MB requested (-42% vs R11).
//  * 512 blocks = 2/CU exact; XCD-bijective swizzle kept.

#define NS_H 1024
#define NS_W 1024
#define RY   32                      // rows per block chunk
#define NCH  32                      // chunks per (batch, x-tile): 1022/32 -> 32 (tail 30 valid)
#define NBLK 512                     // 8 batches x 2 x-tiles x 32 chunks
#define PARTS_PER_B 64               // 2 x-tiles x 32 chunks

#define GL16(gp, lp) __builtin_amdgcn_global_load_lds( \
    (const __attribute__((address_space(1))) void*)(gp), \
    (__attribute__((address_space(3))) void*)(lp), 16, 0, 0)
#define GL4(gp, lp) __builtin_amdgcn_global_load_lds( \
    (const __attribute__((address_space(1))) void*)(gp), \
    (__attribute__((address_space(3))) void*)(lp), 4, 0, 0)

__device__ __forceinline__ float4 rd4(const float* p) { return *(const float4*)p; }
__device__ __forceinline__ float4 avg4(float4 a, float4 b) {
    return make_float4(0.5f*(a.x+b.x), 0.5f*(a.y+b.y), 0.5f*(a.z+b.z), 0.5f*(a.w+b.w));
}
__device__ __forceinline__ float4 sub4(float4 a, float4 b) {
    return make_float4(a.x-b.x, a.y-b.y, a.z-b.z, a.w-b.w);
}

__global__ __launch_bounds__(128) void ns_loss_partial(
    const float* __restrict__ v_old,
    const float* __restrict__ v_new,
    const float* __restrict__ p,
    const int*   __restrict__ mask,
    float* __restrict__ ws)
{
    // XCD-bijective swizzle over 512 blocks (512 % 8 == 0)
    const int blkp = blockIdx.x;
    const int lg   = (blkp & 7) * (NBLK / 8) + (blkp >> 3);
    const int b    = lg >> 6;            // batch
    const int rem  = lg & 63;
    const int c    = rem >> 1;           // chunk
    const int t    = rem & 1;            // x-tile
    const int y0   = 1 + c * RY;         // output rows y0..y0+31 (tail masked)
    const int gx   = t * 512;

    const size_t hw = (size_t)NS_H * NS_W;
    const float* uo = v_old + (size_t)b * 2 * hw;
    const float* wo = uo + hw;
    const float* un = v_new + (size_t)b * 2 * hw;
    const float* wn = un + hw;
    const float* pb = p    + (size_t)b * hw;
    const float* mbf = (const float*)(mask + (size_t)b * hw);   // raw bit transport

    const int tid = (int)threadIdx.x;    // 0..127
    const int wv  = tid >> 6;            // wave 0/1
    const int ln  = tid & 63;
    const int q0  = tid * 4;             // tile-local col 0..508

    // ring[slot][arr][col]: arr 0=un,1=uo,2=wn,3=wo,4=p,5=mask-bits
    __shared__ float ring[4][6][512];
    __shared__ float es[4][64];          // x-halo: [0..4]=left un,uo,wn,wo,p; [5..8]=right un,uo,wn,wo
    __shared__ float sred[2];

    // stage row-set: global row gr into ring slot
    auto stage_set = [&](int slot, int gr) {
        const size_t rb = (size_t)gr * NS_W + gx;
        if (wv == 0) {
            GL16(un + rb +       (size_t)ln*4, &ring[slot][0][0]);
            GL16(un + rb + 256 + (size_t)ln*4, &ring[slot][0][256]);
            GL16(uo + rb +       (size_t)ln*4, &ring[slot][1][0]);
            GL16(uo + rb + 256 + (size_t)ln*4, &ring[slot][1][256]);
            GL16(wn + rb +       (size_t)ln*4, &ring[slot][2][0]);
            GL16(wn + rb + 256 + (size_t)ln*4, &ring[slot][2][256]);
        } else {
            GL16(wo + rb +       (size_t)ln*4, &ring[slot][3][0]);
            GL16(wo + rb + 256 + (size_t)ln*4, &ring[slot][3][256]);
            GL16(pb + rb +       (size_t)ln*4, &ring[slot][4][0]);
            GL16(pb + rb + 256 + (size_t)ln*4, &ring[slot][4][256]);
            GL16(mbf + rb +       (size_t)ln*4, &ring[slot][5][0]);
            GL16(mbf + rb + 256 + (size_t)ln*4, &ring[slot][5][256]);
            // x-halo gather: 9 lanes fetch edge scalars (clamped; unused edges masked)
            const int xl = (gx == 0) ? 0 : gx - 1;
            const int xr = (gx + 512 <= NS_W - 1) ? gx + 512 : NS_W - 1;
            const size_t rowb = (size_t)gr * NS_W;
            const float* ep;
            switch (ln) {
                case 0: ep = un + rowb + xl; break;
                case 1: ep = uo + rowb + xl; break;
                case 2: ep = wn + rowb + xl; break;
                case 3: ep = wo + rowb + xl; break;
                case 4: ep = pb + rowb + xl; break;
                case 5: ep = un + rowb + xr; break;
                case 6: ep = uo + rowb + xr; break;
                case 7: ep = wn + rowb + xr; break;
                case 8: ep = wo + rowb + xr; break;
                default: ep = pb + rowb + gx; break;
            }
            GL4(ep, &es[slot][0]);
        }
    };

    // ---- prologue: stage sets 0,1,2 (rows y0-1, y0, y0+1) ----
    stage_set(0, y0 - 1);
    stage_set(1, y0);
    stage_set(2, y0 + 1);
    __builtin_amdgcn_sched_barrier(0);

    float acc = 0.f;

    for (int r = 0; r < RY; ++r) {
        __builtin_amdgcn_s_barrier();          // WAR guard: compute r-1 done everywhere
        __builtin_amdgcn_sched_barrier(0);

        if (r < RY - 1) {
            int gr = y0 + r + 2; if (gr > NS_H - 1) gr = NS_H - 1;
            stage_set((r + 3) & 3, gr);        // set r+3, in flight across this compute
            __builtin_amdgcn_sched_barrier(0);
            if (wv == 0) asm volatile("s_waitcnt vmcnt(6)" ::: "memory");
            else         asm volatile("s_waitcnt vmcnt(7)" ::: "memory");
        } else {
            asm volatile("s_waitcnt vmcnt(0)" ::: "memory");
        }
        __builtin_amdgcn_s_barrier();          // all waves' sets <= r+2 resident
        __builtin_amdgcn_sched_barrier(0);

        // ---- stencil row y = y0 + r from LDS sets r, r+1, r+2 ----
        const int sm = r & 3, sc = (r + 1) & 3, sp = (r + 2) & 3;
        const float rv = (y0 + r <= NS_H - 2) ? 1.f : 0.f;

        float4 unc = rd4(&ring[sc][0][q0]), uoc = rd4(&ring[sc][1][q0]);
        float4 wnc = rd4(&ring[sc][2][q0]), woc = rd4(&ring[sc][3][q0]);
        float4 unm = rd4(&ring[sm][0][q0]), uom = rd4(&ring[sm][1][q0]);
        float4 wnm = rd4(&ring[sm][2][q0]), wom = rd4(&ring[sm][3][q0]);
        float4 unp = rd4(&ring[sp][0][q0]), uop = rd4(&ring[sp][1][q0]);
        float4 wnp = rd4(&ring[sp][2][q0]), wop = rd4(&ring[sp][3][q0]);
        float4 pc4 = rd4(&ring[sc][4][q0]);
        float4 pm4 = rd4(&ring[sm][4][q0]);
        float4 mk4 = rd4(&ring[sc][5][q0]);

        float4 u_cv = avg4(unc, uoc), w_cv = avg4(wnc, woc);
        float4 duv  = sub4(unc, uoc), dwv  = sub4(wnc, woc);
        float4 u_mv = avg4(unm, uom), w_mv = avg4(wnm, wom);
        float4 u_pv = avg4(unp, uop), w_pv = avg4(wnp, wop);

        float ul, wl, plv, urr, wrr;
        if (q0 == 0) {
            ul  = 0.5f * (es[sc][0] + es[sc][1]);
            wl  = 0.5f * (es[sc][2] + es[sc][3]);
            plv = es[sc][4];
        } else {
            ul  = 0.5f * (ring[sc][0][q0-1] + ring[sc][1][q0-1]);
            wl  = 0.5f * (ring[sc][2][q0-1] + ring[sc][3][q0-1]);
            plv = ring[sc][4][q0-1];
        }
        if (q0 == 508) {
            urr = 0.5f * (es[sc][5] + es[sc][6]);
            wrr = 0.5f * (es[sc][7] + es[sc][8]);
        } else {
            urr = 0.5f * (ring[sc][0][q0+4] + ring[sc][1][q0+4]);
            wrr = 0.5f * (ring[sc][2][q0+4] + ring[sc][3][q0+4]);
        }

        const float uc[6]  = {ul, u_cv.x, u_cv.y, u_cv.z, u_cv.w, urr};
        const float wcv[6] = {wl, w_cv.x, w_cv.y, w_cv.z, w_cv.w, wrr};
        const float uym[4] = {u_mv.x, u_mv.y, u_mv.z, u_mv.w};
        const float uyp[4] = {u_pv.x, u_pv.y, u_pv.z, u_pv.w};
        const float wym[4] = {w_mv.x, w_mv.y, w_mv.z, w_mv.w};
        const float wyp[4] = {w_pv.x, w_pv.y, w_pv.z, w_pv.w};
        const float du[4]  = {duv.x, duv.y, duv.z, duv.w};
        const float dw[4]  = {dwv.x, dwv.y, dwv.z, dwv.w};
        const float pcv[5] = {plv, pc4.x, pc4.y, pc4.z, pc4.w};
        const float pym[4] = {pm4.x, pm4.y, pm4.z, pm4.w};
        const unsigned mm[4] = {__float_as_uint(mk4.x), __float_as_uint(mk4.y),
                                __float_as_uint(mk4.z), __float_as_uint(mk4.w)};

        #pragma unroll
        for (int j = 0; j < 4; ++j) {
            const int x = gx + q0 + j;
            const float m = ((x >= 1 && x <= NS_W - 2) ? (float)mm[j] : 0.f) * rv;
            const float u_cc = uc[j+1],  u_xm = uc[j],  u_xp = uc[j+2];
            const float w_cc = wcv[j+1], w_xm = wcv[j], w_xp = wcv[j+2];

            float res_x =
                dw[j] * 0.25f
              + w_cc * 0.5f * (w_xp - w_xm)
              + 0.5f * ( 0.5f * (u_cc + u_xm) * (w_cc   - wym[j])
                       + 0.5f * (u_cc + u_xp) * (wyp[j] - w_cc  ) )
              + (pcv[j+1] - pcv[j])
              - 0.1f * (w_xm + w_xp + wym[j] + wyp[j] - 4.f * w_cc);

            float res_y =
                du[j] * 0.25f
              + u_cc * 0.5f * (uyp[j] - uym[j])
              + 0.5f * ( 0.5f * (w_cc + wym[j]) * (u_cc - u_xm)
                       + 0.5f * (w_cc + wyp[j]) * (u_xp - u_cc) )
              + (pcv[j+1] - pym[j])
              - 0.1f * (u_xm + u_xp + uym[j] + uyp[j] - 4.f * u_cc);

            acc += m * (res_x * res_x + res_y * res_y);
        }
    }

    // ---- block reduction: 2 waves ----
    #pragma unroll
    for (int off = 32; off > 0; off >>= 1)
        acc += __shfl_down(acc, off);

    if (ln == 0) sred[wv] = acc;
    __syncthreads();

    if (tid == 0)
        ws[lg] = sred[0] + sred[1];
}

__global__ __launch_bounds__(64) void ns_loss_reduce(
    const float* __restrict__ ws, float* __restrict__ out)
{
    const int b = blockIdx.x;
    float a = ws[b * PARTS_PER_B + threadIdx.x];

    #pragma unroll
    for (int off = 32; off > 0; off >>= 1)
        a += __shfl_down(a, off);

    if (threadIdx.x == 0) {
        const float inv = 1.0f / ((float)(NS_H - 2) * (float)(NS_W - 2));
        out[b] = a * inv;
    }
}

extern "C" void kernel_launch(void* const* d_in, const int* in_sizes, int n_in,
                              void* d_out, int out_size, void* d_ws, size_t ws_size,
                              hipStream_t stream) {
    const float* v_old = (const float*)d_in[0];
    const float* v_new = (const float*)d_in[1];
    const float* p_new = (const float*)d_in[2];
    const int*   msk   = (const int*)d_in[3];
    float* out = (float*)d_out;
    float* ws  = (float*)d_ws;

    const int B = out_size;   // 8

    ns_loss_partial<<<dim3(NBLK), dim3(128), 0, stream>>>(v_old, v_new, p_new, msk, ws);
    ns_loss_reduce<<<dim3(B), dim3(64), 0, stream>>>(ws, out);
}